// Round 3
// baseline (371.398 us; speedup 1.0000x reference)
//
#include <hip/hip_runtime.h>

// QuaternionLinear as one 4096^3 bf16 GEMM (B^T layout).
// Round 3: back to 16x16x32 MFMA (32x32 tripled LDS bank conflicts);
// BK=64 to halve barrier-drain count; XOR-swizzled LDS (16B chunks,
// chunk' = chunk ^ (row&7)) to make fragment reads bank-conflict-free.
// Swizzle is applied by permuting the GLOBAL SOURCE chunk per lane, since
// global_load_lds forces LDS dst = wave-uniform base + lane*16B.

typedef __bf16 bf16x8 __attribute__((ext_vector_type(8)));
typedef float floatx4 __attribute__((ext_vector_type(4)));

constexpr int M = 4096;   // batch
constexpr int N = 4096;   // out_f * 4
constexpr int K = 4096;   // in_f * 4
constexpr int BM = 128, BN = 128, BK = 64;

constexpr int CVT_BLOCKS = (M * K / 8) / 256;        // 8192: x fp32 -> bf16
constexpr int EXP_BLOCKS = (1024 * 1024 / 2) / 256;  // 2048: w -> signed Wbig

// ---------- fused prep: x -> A (bf16), w -> Wbig (sign-expanded bf16) ----------
// Wbig rows (c order) per quaternion w=(r,i,j,k):
//   d=0: [+r,-i,-j,-k]  d=1: [+i,+r,+k,-j]  d=2: [+j,-k,+r,+i]  d=3: [+k,+j,-i,+r]
__global__ void prep_kernel(const float* __restrict__ x, const float* __restrict__ w,
                            __bf16* __restrict__ A, __bf16* __restrict__ Wb) {
    const int b = blockIdx.x;
    if (b < CVT_BLOCKS) {
        const size_t i = (size_t)b * 256 + threadIdx.x;   // 8 elems/thread
        const float4* xp = (const float4*)x;
        float4 a = xp[2 * i];
        float4 c = xp[2 * i + 1];
        bf16x8 v;
        v[0] = (__bf16)a.x; v[1] = (__bf16)a.y; v[2] = (__bf16)a.z; v[3] = (__bf16)a.w;
        v[4] = (__bf16)c.x; v[5] = (__bf16)c.y; v[6] = (__bf16)c.z; v[7] = (__bf16)c.w;
        *(bf16x8*)(A + 8 * i) = v;
    } else {
        const int idx = (b - CVT_BLOCKS) * 256 + threadIdx.x;  // quaternion PAIR index
        const int o  = idx >> 9;
        const int ip = (idx & 511) * 2;
        float4 q0 = ((const float4*)w)[o * 1024 + ip];
        float4 q1 = ((const float4*)w)[o * 1024 + ip + 1];
        __bf16* base = Wb + (size_t)(o * 4) * K + ip * 4;
        bf16x8 r;
        r[0] = (__bf16)q0.x; r[1] = (__bf16)(-q0.y); r[2] = (__bf16)(-q0.z); r[3] = (__bf16)(-q0.w);
        r[4] = (__bf16)q1.x; r[5] = (__bf16)(-q1.y); r[6] = (__bf16)(-q1.z); r[7] = (__bf16)(-q1.w);
        *(bf16x8*)(base) = r;
        r[0] = (__bf16)q0.y; r[1] = (__bf16)q0.x; r[2] = (__bf16)q0.w; r[3] = (__bf16)(-q0.z);
        r[4] = (__bf16)q1.y; r[5] = (__bf16)q1.x; r[6] = (__bf16)q1.w; r[7] = (__bf16)(-q1.z);
        *(bf16x8*)(base + (size_t)K) = r;
        r[0] = (__bf16)q0.z; r[1] = (__bf16)(-q0.w); r[2] = (__bf16)q0.x; r[3] = (__bf16)q0.y;
        r[4] = (__bf16)q1.z; r[5] = (__bf16)(-q1.w); r[6] = (__bf16)q1.x; r[7] = (__bf16)q1.y;
        *(bf16x8*)(base + (size_t)2 * K) = r;
        r[0] = (__bf16)q0.w; r[1] = (__bf16)q0.z; r[2] = (__bf16)(-q0.y); r[3] = (__bf16)q0.x;
        r[4] = (__bf16)q1.w; r[5] = (__bf16)q1.z; r[6] = (__bf16)(-q1.y); r[7] = (__bf16)q1.x;
        *(bf16x8*)(base + (size_t)3 * K) = r;
    }
}

// ---------- async global->LDS, 16B per lane ----------
__device__ __forceinline__ void gload_lds16(const __bf16* g, __bf16* l) {
    __builtin_amdgcn_global_load_lds(
        (const __attribute__((address_space(1))) void*)g,
        (__attribute__((address_space(3))) void*)l, 16, 0, 0);
}

// ---------- GEMM: C[M][N] = A[M][K] * B[N][K]^T + bias[N] ----------
__global__ void qgemm_kernel(const __bf16* __restrict__ A,
                             const __bf16* __restrict__ B,
                             const float* __restrict__ bias,
                             float* __restrict__ C) {
    __shared__ __bf16 As[BM][BK];   // 16 KB, rows of 8 x 16B chunks, XOR-swizzled
    __shared__ __bf16 Bs[BN][BK];   // 16 KB

    const int tid  = threadIdx.x;
    const int wave = tid >> 6;
    const int lane = tid & 63;
    const int bm = blockIdx.y * BM;
    const int bn = blockIdx.x * BN;
    const int wm = (wave & 1) * 64;   // wave's 64x64 C-subtile origin
    const int wn = (wave >> 1) * 64;

    // staging: one issue = 64 lanes x 16B = 8 rows x 128B. lane -> (row, chunk).
    // LDS chunk (lane&7) receives global chunk (lane&7)^srow  => LDS chunk c
    // of row r holds global chunk c ^ (r&7).
    const int srow   = lane >> 3;               // 0..7
    const int schunk = (lane & 7) ^ srow;       // swizzled global source chunk

    // 4 issues each for A and B per K-iter; issue i covers rows i*32 + wave*8 + srow
    const __bf16* ag[4];
    const __bf16* bg[4];
    __bf16* as[4];
    __bf16* bs[4];
#pragma unroll
    for (int i = 0; i < 4; ++i) {
        const int rbase = i * 32 + wave * 8;
        ag[i] = A + (size_t)(bm + rbase + srow) * K + schunk * 8;
        bg[i] = B + (size_t)(bn + rbase + srow) * K + schunk * 8;
        as[i] = &As[rbase][0];   // wave-uniform base; HW adds lane*16B
        bs[i] = &Bs[rbase][0];
    }

    floatx4 acc[4][4] = {};

    const int fl = lane & 15;          // m (A) / n (B) index within 16
    const int fq = lane >> 4;          // k-quad 0..3 (8 elems each)
    const int x7 = fl & 7;             // swizzle term: r&7 == fl&7 for all frag rows

    for (int k0 = 0; k0 < K; k0 += BK) {
#pragma unroll
        for (int i = 0; i < 4; ++i) gload_lds16(ag[i] + k0, as[i]);
#pragma unroll
        for (int i = 0; i < 4; ++i) gload_lds16(bg[i] + k0, bs[i]);
        __syncthreads();

#pragma unroll
        for (int ks = 0; ks < 2; ++ks) {              // two MFMA k-steps of 32
            const int chunk = ((ks * 4) | fq) ^ x7;   // swizzled LDS chunk
            bf16x8 af[4], bfr[4];
#pragma unroll
            for (int t = 0; t < 4; ++t)
                af[t] = *(const bf16x8*)&As[wm + t * 16 + fl][chunk * 8];
#pragma unroll
            for (int t = 0; t < 4; ++t)
                bfr[t] = *(const bf16x8*)&Bs[wn + t * 16 + fl][chunk * 8];

#pragma unroll
            for (int mt = 0; mt < 4; ++mt)
#pragma unroll
                for (int nt = 0; nt < 4; ++nt)
                    acc[mt][nt] = __builtin_amdgcn_mfma_f32_16x16x32_bf16(
                        af[mt], bfr[nt], acc[mt][nt], 0, 0, 0);
        }
        __syncthreads();
    }

    // epilogue: C/D layout col = lane&15, row = (lane>>4)*4 + reg  (verified R1)
#pragma unroll
    for (int mt = 0; mt < 4; ++mt) {
        const int row = bm + wm + mt * 16 + fq * 4;
#pragma unroll
        for (int nt = 0; nt < 4; ++nt) {
            const int col = bn + wn + nt * 16 + fl;
            const float bv = bias[col];
            float* cp = C + (size_t)row * N + col;
#pragma unroll
            for (int r = 0; r < 4; ++r)
                cp[(size_t)r * N] = acc[mt][nt][r] + bv;
        }
    }
}

extern "C" void kernel_launch(void* const* d_in, const int* in_sizes, int n_in,
                              void* d_out, int out_size, void* d_ws, size_t ws_size,
                              hipStream_t stream) {
    const float* x    = (const float*)d_in[0];   // (4096,1024,4) fp32
    const float* w    = (const float*)d_in[1];   // (1024,1024,4) fp32
    const float* bias = (const float*)d_in[2];   // (1024,4) fp32
    float* out = (float*)d_out;                  // (4096,1024,4) fp32

    __bf16* Abf  = (__bf16*)d_ws;                                   // 32 MB
    __bf16* Wbig = (__bf16*)((char*)d_ws + (size_t)M * K * 2);      // 32 MB

    prep_kernel<<<CVT_BLOCKS + EXP_BLOCKS, 256, 0, stream>>>(x, w, Abf, Wbig);

    dim3 grid(N / BN, M / BM);  // 32 x 32
    qgemm_kernel<<<grid, 256, 0, stream>>>(Abf, Wbig, bias, out);
}

// Round 4
// 296.396 us; speedup vs baseline: 1.2530x; 1.2530x over previous
//
#include <hip/hip_runtime.h>

// QuaternionLinear as one 4096^3 bf16 GEMM (B^T layout).
// Round 4: R1 structure (BK=32, 16x16x32 MFMA, VGPR~56, no spill) +
//  (a) conflict-free XOR swizzle: LDS chunk c of row r holds global chunk
//      c ^ ((r>>1)&3); applied via source permutation (global_load_lds dst
//      is forced contiguous). Frag reads then hit all 8 bank-groups/cycle.
//  (b) XCD-aware block remap: bid&7 = XCD owns a 16(M) x 8(N) tile region,
//      M-fastest so co-resident blocks share a B-panel in per-XCD L2.

typedef __bf16 bf16x8 __attribute__((ext_vector_type(8)));
typedef float floatx4 __attribute__((ext_vector_type(4)));

constexpr int M = 4096;   // batch
constexpr int N = 4096;   // out_f * 4
constexpr int K = 4096;   // in_f * 4
constexpr int BM = 128, BN = 128, BK = 32;

constexpr int CVT_BLOCKS = (M * K / 8) / 256;        // 8192: x fp32 -> bf16
constexpr int EXP_BLOCKS = (1024 * 1024 / 2) / 256;  // 2048: w -> signed Wbig

// ---------- fused prep: x -> A (bf16), w -> Wbig (sign-expanded bf16) ----------
// Wbig rows (c order) per quaternion w=(r,i,j,k):
//   d=0: [+r,-i,-j,-k]  d=1: [+i,+r,+k,-j]  d=2: [+j,-k,+r,+i]  d=3: [+k,+j,-i,+r]
__global__ void prep_kernel(const float* __restrict__ x, const float* __restrict__ w,
                            __bf16* __restrict__ A, __bf16* __restrict__ Wb) {
    const int b = blockIdx.x;
    if (b < CVT_BLOCKS) {
        const size_t i = (size_t)b * 256 + threadIdx.x;   // 8 elems/thread
        const float4* xp = (const float4*)x;
        float4 a = xp[2 * i];
        float4 c = xp[2 * i + 1];
        bf16x8 v;
        v[0] = (__bf16)a.x; v[1] = (__bf16)a.y; v[2] = (__bf16)a.z; v[3] = (__bf16)a.w;
        v[4] = (__bf16)c.x; v[5] = (__bf16)c.y; v[6] = (__bf16)c.z; v[7] = (__bf16)c.w;
        *(bf16x8*)(A + 8 * i) = v;
    } else {
        const int idx = (b - CVT_BLOCKS) * 256 + threadIdx.x;  // quaternion PAIR index
        const int o  = idx >> 9;
        const int ip = (idx & 511) * 2;
        float4 q0 = ((const float4*)w)[o * 1024 + ip];
        float4 q1 = ((const float4*)w)[o * 1024 + ip + 1];
        __bf16* base = Wb + (size_t)(o * 4) * K + ip * 4;
        bf16x8 r;
        r[0] = (__bf16)q0.x; r[1] = (__bf16)(-q0.y); r[2] = (__bf16)(-q0.z); r[3] = (__bf16)(-q0.w);
        r[4] = (__bf16)q1.x; r[5] = (__bf16)(-q1.y); r[6] = (__bf16)(-q1.z); r[7] = (__bf16)(-q1.w);
        *(bf16x8*)(base) = r;
        r[0] = (__bf16)q0.y; r[1] = (__bf16)q0.x; r[2] = (__bf16)q0.w; r[3] = (__bf16)(-q0.z);
        r[4] = (__bf16)q1.y; r[5] = (__bf16)q1.x; r[6] = (__bf16)q1.w; r[7] = (__bf16)(-q1.z);
        *(bf16x8*)(base + (size_t)K) = r;
        r[0] = (__bf16)q0.z; r[1] = (__bf16)(-q0.w); r[2] = (__bf16)q0.x; r[3] = (__bf16)q0.y;
        r[4] = (__bf16)q1.z; r[5] = (__bf16)(-q1.w); r[6] = (__bf16)q1.x; r[7] = (__bf16)q1.y;
        *(bf16x8*)(base + (size_t)2 * K) = r;
        r[0] = (__bf16)q0.w; r[1] = (__bf16)q0.z; r[2] = (__bf16)(-q0.y); r[3] = (__bf16)q0.x;
        r[4] = (__bf16)q1.w; r[5] = (__bf16)q1.z; r[6] = (__bf16)(-q1.y); r[7] = (__bf16)q1.x;
        *(bf16x8*)(base + (size_t)3 * K) = r;
    }
}

// ---------- async global->LDS, 16B per lane ----------
__device__ __forceinline__ void gload_lds16(const __bf16* g, __bf16* l) {
    __builtin_amdgcn_global_load_lds(
        (const __attribute__((address_space(1))) void*)g,
        (__attribute__((address_space(3))) void*)l, 16, 0, 0);
}

// ---------- GEMM: C[M][N] = A[M][K] * B[N][K]^T + bias[N] ----------
__global__ void qgemm_kernel(const __bf16* __restrict__ A,
                             const __bf16* __restrict__ B,
                             const float* __restrict__ bias,
                             float* __restrict__ C) {
    __shared__ __bf16 As[BM][BK];
    __shared__ __bf16 Bs[BN][BK];

    const int tid  = threadIdx.x;
    const int wave = tid >> 6;
    const int lane = tid & 63;

    // XCD-aware remap: xcd = bid&7 owns a 16x8 region of the 32x32 tile grid,
    // M-index fastest (16 consecutive same-XCD blocks share one B-panel).
    const int bid = blockIdx.x;
    const int xcd = bid & 7;
    const int q   = bid >> 3;                       // 0..127
    const int ty  = (xcd >> 2) * 16 + (q & 15);     // 0..31  (M tile)
    const int tx  = (xcd & 3) * 8 + (q >> 4);       // 0..31  (N tile)
    const int bm = ty * BM;
    const int bn = tx * BN;

    const int wm = (wave & 1) * 64;   // wave's C-subtile origin
    const int wn = (wave >> 1) * 64;

    // staging: each issue = 16 rows x 64B. lane -> (row = lane>>2, chunk slot lane&3).
    // source chunk = slot ^ ((row>>1)&3)  =>  LDS chunk c of row r = global chunk c^((r>>1)&3)
    const int ldrow = lane >> 2;
    const int sc    = (lane & 3) ^ ((lane >> 3) & 3);
    const int ldcol = sc * 8;

    const __bf16* ag0 = A + (size_t)(bm + wave * 16 + ldrow) * K + ldcol;
    const __bf16* ag1 = ag0 + (size_t)64 * K;
    const __bf16* bg0 = B + (size_t)(bn + wave * 16 + ldrow) * K + ldcol;
    const __bf16* bg1 = bg0 + (size_t)64 * K;

    __bf16* as0 = &As[wave * 16][0];        // wave-uniform base; HW adds lane*16B
    __bf16* as1 = &As[64 + wave * 16][0];
    __bf16* bs0 = &Bs[wave * 16][0];
    __bf16* bs1 = &Bs[64 + wave * 16][0];

    floatx4 acc[4][4] = {};

    const int fl  = lane & 15;                      // m (A) / n (B) index within 16
    const int fq  = lane >> 4;                      // global 16B chunk 0..3
    const int fco = (fq ^ ((fl >> 1) & 3)) * 8;     // swizzled LDS element offset

    for (int k0 = 0; k0 < K; k0 += BK) {
        gload_lds16(ag0 + k0, as0);
        gload_lds16(ag1 + k0, as1);
        gload_lds16(bg0 + k0, bs0);
        gload_lds16(bg1 + k0, bs1);
        __syncthreads();

        bf16x8 af[4], bfr[4];
#pragma unroll
        for (int t = 0; t < 4; ++t)
            af[t] = *(const bf16x8*)&As[wm + t * 16 + fl][fco];
#pragma unroll
        for (int t = 0; t < 4; ++t)
            bfr[t] = *(const bf16x8*)&Bs[wn + t * 16 + fl][fco];

#pragma unroll
        for (int mt = 0; mt < 4; ++mt)
#pragma unroll
            for (int nt = 0; nt < 4; ++nt)
                acc[mt][nt] = __builtin_amdgcn_mfma_f32_16x16x32_bf16(
                    af[mt], bfr[nt], acc[mt][nt], 0, 0, 0);
        __syncthreads();
    }

    // epilogue: C/D layout col = lane&15, row = (lane>>4)*4 + reg  (verified R1)
#pragma unroll
    for (int mt = 0; mt < 4; ++mt) {
        const int row = bm + wm + mt * 16 + fq * 4;
#pragma unroll
        for (int nt = 0; nt < 4; ++nt) {
            const int col = bn + wn + nt * 16 + fl;
            const float bv = bias[col];
            float* cp = C + (size_t)row * N + col;
#pragma unroll
            for (int r = 0; r < 4; ++r)
                cp[(size_t)r * N] = acc[mt][nt][r] + bv;
        }
    }
}

extern "C" void kernel_launch(void* const* d_in, const int* in_sizes, int n_in,
                              void* d_out, int out_size, void* d_ws, size_t ws_size,
                              hipStream_t stream) {
    const float* x    = (const float*)d_in[0];   // (4096,1024,4) fp32
    const float* w    = (const float*)d_in[1];   // (1024,1024,4) fp32
    const float* bias = (const float*)d_in[2];   // (1024,4) fp32
    float* out = (float*)d_out;                  // (4096,1024,4) fp32

    __bf16* Abf  = (__bf16*)d_ws;                                   // 32 MB
    __bf16* Wbig = (__bf16*)((char*)d_ws + (size_t)M * K * 2);      // 32 MB

    prep_kernel<<<CVT_BLOCKS + EXP_BLOCKS, 256, 0, stream>>>(x, w, Abf, Wbig);

    qgemm_kernel<<<1024, 256, 0, stream>>>(Abf, Wbig, bias, out);
}